// Round 12
// baseline (387.899 us; speedup 1.0000x reference)
//
#include <hip/hip_runtime.h>
#include <hip/hip_bf16.h>

#define N_NODES 100000
#define N_EDGES 1600000
#define DIM 64
#define N_LAYERS 5
#define N_GRAPHS 256

#define NB2 196        // coarse buckets of 512 nodes
#define SUBCAP2 9216   // per-bucket pair capacity: mean 8192, sigma ~90
#define CAP2 12800     // esrc region per bucket (padded CSR worst case)
#define DUMMY N_NODES  // dummy node id; its h row is kept zero
#define TILE 3200      // edges per binning workgroup
#define NTILE 500      // 500 * 3200 = 1.6M
#define MTILES (N_NODES / 16)  // 6250 node-tiles for the MFMA MLP

typedef __attribute__((ext_vector_type(8))) short short8;
typedef __attribute__((ext_vector_type(4))) float float4v;

// bf16 helpers (bit-level, RNE)
__device__ __forceinline__ unsigned short f2bf(float f) {
    unsigned int u = __float_as_uint(f);
    unsigned int r = (u + 0x7fffu + ((u >> 16) & 1u)) >> 16;
    return (unsigned short)r;
}
__device__ __forceinline__ float bf2f(unsigned short b) {
    return __uint_as_float(((unsigned int)b) << 16);
}

// Fused init: x->bf16, weight prepack (B-frag order, hi/lo split), dummy rows,
// bcursor zero, pooled staging zero. One launch replaces four.
__global__ __launch_bounds__(256) void cvt_init_kernel(
    const float4* __restrict__ x, ushort4* __restrict__ hb,
    const float* __restrict__ Ws1, const float* __restrict__ Ws2,
    unsigned short* __restrict__ wpk,
    unsigned short* __restrict__ hbfA, unsigned short* __restrict__ hbfB,
    int* __restrict__ bcursor, float* __restrict__ pooled, int n4) {
    int i = blockIdx.x * blockDim.x + threadIdx.x;
    if (i < n4) {
        float4 v = x[i];
        ushort4 o;
        o.x = f2bf(v.x); o.y = f2bf(v.y); o.z = f2bf(v.z); o.w = f2bf(v.w);
        hb[i] = o;
    }
    if (i < N_LAYERS * 32 * 64) {
        int lane = i & 63;
        int frag = (i >> 6) & 31;
        int l = i >> 11;
        int kf = frag & 1;
        int nt = (frag >> 1) & 3;
        int split = (frag >> 3) & 1;
        int mat = (frag >> 4) & 1;
        const float* W = (mat ? Ws2 : Ws1) + (size_t)l * DIM * DIM;
        unsigned short outv[8];
#pragma unroll
        for (int j = 0; j < 8; ++j) {
            int k = kf * 32 + ((lane >> 4) << 3) + j;
            int n = nt * 16 + (lane & 15);
            float v = W[k * DIM + n];
            unsigned short hi = f2bf(v);
            outv[j] = split ? f2bf(v - bf2f(hi)) : hi;
        }
        ushort4* dst = (ushort4*)(wpk + ((size_t)(l * 32 + frag) * 64 + lane) * 8);
        dst[0] = make_ushort4(outv[0], outv[1], outv[2], outv[3]);
        dst[1] = make_ushort4(outv[4], outv[5], outv[6], outv[7]);
    }
    if (i < N_GRAPHS * DIM) pooled[i] = 0.f;
    if (i < NB2) bcursor[i] = 0;
    if (i < DIM) {
        hbfA[(size_t)DUMMY * DIM + i] = 0;
        hbfB[(size_t)DUMMY * DIM + i] = 0;
    }
}

// Phase A: tile-binning with run reservation (one global atomic per bucket per tile).
__global__ __launch_bounds__(256) void bin_kernel(
    const int* __restrict__ src, const int* __restrict__ dst,
    int* __restrict__ bcursor, int* __restrict__ pairbuf) {
    __shared__ int hcnt[NB2];
    __shared__ int gbase[NB2];
    __shared__ int lcur[NB2];
    const int tid = threadIdx.x;
    const int base = blockIdx.x * TILE;

    for (int l = tid; l < NB2; l += 256) { hcnt[l] = 0; lcur[l] = 0; }
    __syncthreads();
    for (int j = tid; j < TILE; j += 256) {
        int d = dst[base + j];
        atomicAdd(&hcnt[d >> 9], 1);
    }
    __syncthreads();
    for (int l = tid; l < NB2; l += 256)
        gbase[l] = atomicAdd(&bcursor[l], hcnt[l]);
    __syncthreads();
    for (int j = tid; j < TILE; j += 256) {
        int s = src[base + j];
        int d = dst[base + j];
        int b = d >> 9;
        int r = atomicAdd(&lcur[b], 1);
        int pos = gbase[b] + r;
        if (pos < SUBCAP2) pairbuf[b * SUBCAP2 + pos] = (s << 9) | (d & 511);
    }
}

// Phase B: one WG per coarse bucket (512 nodes). Count -> padded scan -> scatter.
__global__ __launch_bounds__(256) void csr_kernel(
    const int* __restrict__ bcursor, const int* __restrict__ pairbuf,
    int* __restrict__ esrc, int2* __restrict__ meta) {
    __shared__ int lcnt[512];
    __shared__ int loff[512];
    __shared__ int lcur[512];
    __shared__ int s2[256];
    const int b = blockIdx.x;
    const int tid = threadIdx.x;
    int ec = bcursor[b];
    if (ec > SUBCAP2) ec = SUBCAP2;
    const int* pp = pairbuf + b * SUBCAP2;

    for (int l = tid; l < 512; l += 256) lcnt[l] = 0;
    __syncthreads();
    for (int j = tid; j < ec; j += 256) atomicAdd(&lcnt[pp[j] & 511], 1);
    __syncthreads();

    int c0 = (lcnt[2 * tid] + 7) & ~7;
    int c1 = (lcnt[2 * tid + 1] + 7) & ~7;
    s2[tid] = c0 + c1;
    __syncthreads();
    for (int off = 1; off < 256; off <<= 1) {
        int v = (tid >= off) ? s2[tid - off] : 0;
        __syncthreads();
        s2[tid] += v;
        __syncthreads();
    }
    int exc = s2[tid] - (c0 + c1);
    loff[2 * tid] = exc;
    loff[2 * tid + 1] = exc + c0;
    __syncthreads();

    int* eb = esrc + (size_t)b * CAP2;
    for (int l = tid; l < 512; l += 256) {
        int st = loff[l];
        int cn = lcnt[l];
        int cp = (cn + 7) & ~7;
        lcur[l] = st;
        int node = b * 512 + l;
        if (node < N_NODES) meta[node] = make_int2(b * CAP2 + st, cp);
        for (int j = cn; j < cp; ++j) eb[st + j] = DUMMY;
    }
    __syncthreads();

    for (int j = tid; j < ec; j += 256) {
        int p = pp[j];
        int pos = atomicAdd(&lcur[p & 511], 1);
        eb[pos] = p >> 9;
    }
}

__device__ __forceinline__ void acc8(float* acc, uint4 v) {
    acc[0] += __uint_as_float(v.x << 16);
    acc[1] += __uint_as_float(v.x & 0xffff0000u);
    acc[2] += __uint_as_float(v.y << 16);
    acc[3] += __uint_as_float(v.y & 0xffff0000u);
    acc[4] += __uint_as_float(v.z << 16);
    acc[5] += __uint_as_float(v.z & 0xffff0000u);
    acc[6] += __uint_as_float(v.w << 16);
    acc[7] += __uint_as_float(v.w & 0xffff0000u);
}

// Aggregation: z_i = h_i + sum_j h_j, h rows bf16 (128 B). (R11-proven)
__global__ __launch_bounds__(256) void agg_kernel(
    const unsigned short* __restrict__ hin, unsigned short* __restrict__ z,
    const int2* __restrict__ meta, const int* __restrict__ esrc, int n_nodes) {
    __shared__ float zbuf[4][2][8][DIM];  // 16 KB
    const int lane = threadIdx.x & 63;
    const int wv = threadIdx.x >> 6;
    const int grp = lane >> 3;
    const int sub = lane & 7;
    const int wave_id = (blockIdx.x * blockDim.x + threadIdx.x) >> 6;
    const int n_waves = (gridDim.x * blockDim.x) >> 6;
    const uint4* __restrict__ h4 = (const uint4*)hin;

    for (int ii = wave_id; 2 * ii < n_nodes; ii += n_waves) {
        const int iA = 2 * ii;
        const int iB = iA + 1;
        const int2 mA = meta[iA];
        const int2 mB = meta[iB];
        const float selfA = bf2f(hin[iA * DIM + lane]);
        const float selfB = bf2f(hin[iB * DIM + lane]);
        const int* eA = esrc + mA.x + grp;
        const int* eB = esrc + mB.x + grp;
        const int nA = mA.y, nB = mB.y;

        float accA[8], accB[8];
#pragma unroll
        for (int j = 0; j < 8; ++j) { accA[j] = 0.f; accB[j] = 0.f; }

        int k = 0;
        const int nmin = (nA < nB) ? nA : nB;
        for (; k < nmin; k += 8) {
            const int ia = eA[k];
            const int ib = eB[k];
            uint4 va = h4[ia * 8 + sub];
            uint4 vb = h4[ib * 8 + sub];
            acc8(accA, va);
            acc8(accB, vb);
        }
        for (int kk = k; kk < nA; kk += 8) {
            uint4 va = h4[eA[kk] * 8 + sub];
            acc8(accA, va);
        }
        for (int kk = k; kk < nB; kk += 8) {
            uint4 vb = h4[eB[kk] * 8 + sub];
            acc8(accB, vb);
        }

        *((float4*)&zbuf[wv][0][grp][sub * 8 + 0]) = make_float4(accA[0], accA[1], accA[2], accA[3]);
        *((float4*)&zbuf[wv][0][grp][sub * 8 + 4]) = make_float4(accA[4], accA[5], accA[6], accA[7]);
        *((float4*)&zbuf[wv][1][grp][sub * 8 + 0]) = make_float4(accB[0], accB[1], accB[2], accB[3]);
        *((float4*)&zbuf[wv][1][grp][sub * 8 + 4]) = make_float4(accB[4], accB[5], accB[6], accB[7]);
        __builtin_amdgcn_wave_barrier();
        float zA = selfA, zB = selfB;
#pragma unroll
        for (int g = 0; g < 8; ++g) {
            zA += zbuf[wv][0][g][lane];
            zB += zbuf[wv][1][g][lane];
        }
        z[iA * DIM + lane] = f2bf(zA);
        z[iB * DIM + lane] = f2bf(zB);
        __builtin_amdgcn_wave_barrier();
    }
}

__device__ __forceinline__ short8 load_frag(const unsigned short* __restrict__ wl, int frag, int lane) {
    union { uint4 u; short8 s; } c;
    c.u = *(const uint4*)(wl + ((size_t)(frag * 64 + lane)) * 8);
    return c.s;
}

__device__ __forceinline__ void split8(const float* v, short8& hi, short8& lo) {
#pragma unroll
    for (int j = 0; j < 8; ++j) {
        unsigned short h = f2bf(v[j]);
        hi[j] = (short)h;
        lo[j] = (short)f2bf(v[j] - bf2f(h));
    }
}

// MFMA MLP: h = relu(z@W1+b1)@W2+b2 ; z bf16 in, h bf16 out. (R11-proven)
__global__ __launch_bounds__(256) void mlp_mfma_kernel(
    const unsigned short* __restrict__ z, unsigned short* __restrict__ hout,
    const unsigned short* __restrict__ wl,
    const float* __restrict__ b1, const float* __restrict__ b2) {
    __shared__ float tbuf[4][16][68];
    const int lane = threadIdx.x & 63;
    const int wv = threadIdx.x >> 6;
    const int m = lane & 15;
    const int quad = lane >> 4;
    const int wave_id = (blockIdx.x * blockDim.x + threadIdx.x) >> 6;
    const int n_waves = (gridDim.x * blockDim.x) >> 6;

    float b1v[4], b2v[4];
#pragma unroll
    for (int nt = 0; nt < 4; ++nt) {
        b1v[nt] = b1[nt * 16 + m];
        b2v[nt] = b2[nt * 16 + m];
    }

    for (int tile = wave_id; tile < MTILES; tile += n_waves) {
        const int node0 = tile * 16;

        short8 a1[2];
#pragma unroll
        for (int kf = 0; kf < 2; ++kf) {
            union { uint4 u; short8 s; } c;
            c.u = *(const uint4*)(z + ((size_t)(node0 + m)) * DIM + kf * 32 + quad * 8);
            a1[kf] = c.s;
        }

        float4v acc1[4] = {};
#pragma unroll
        for (int nt = 0; nt < 4; ++nt) {
#pragma unroll
            for (int kf = 0; kf < 2; ++kf) {
                short8 bhi = load_frag(wl, ((0 * 2 + 0) * 4 + nt) * 2 + kf, lane);
                short8 blo = load_frag(wl, ((0 * 2 + 1) * 4 + nt) * 2 + kf, lane);
                acc1[nt] = __builtin_amdgcn_mfma_f32_16x16x32_bf16(a1[kf], bhi, acc1[nt], 0, 0, 0);
                acc1[nt] = __builtin_amdgcn_mfma_f32_16x16x32_bf16(a1[kf], blo, acc1[nt], 0, 0, 0);
            }
        }

#pragma unroll
        for (int nt = 0; nt < 4; ++nt) {
#pragma unroll
            for (int r = 0; r < 4; ++r) {
                float tv = acc1[nt][r] + b1v[nt];
                tbuf[wv][quad * 4 + r][nt * 16 + m] = fmaxf(tv, 0.f);
            }
        }
        __builtin_amdgcn_wave_barrier();

        short8 a2hi[2], a2lo[2];
#pragma unroll
        for (int kf = 0; kf < 2; ++kf) {
            const float4* tp = (const float4*)&tbuf[wv][m][kf * 32 + quad * 8];
            float4 t0 = tp[0];
            float4 t1 = tp[1];
            float v[8] = {t0.x, t0.y, t0.z, t0.w, t1.x, t1.y, t1.z, t1.w};
            split8(v, a2hi[kf], a2lo[kf]);
        }
        __builtin_amdgcn_wave_barrier();

        float4v acc2[4] = {};
#pragma unroll
        for (int nt = 0; nt < 4; ++nt) {
#pragma unroll
            for (int kf = 0; kf < 2; ++kf) {
                short8 bhi = load_frag(wl, ((1 * 2 + 0) * 4 + nt) * 2 + kf, lane);
                short8 blo = load_frag(wl, ((1 * 2 + 1) * 4 + nt) * 2 + kf, lane);
                acc2[nt] = __builtin_amdgcn_mfma_f32_16x16x32_bf16(a2hi[kf], bhi, acc2[nt], 0, 0, 0);
                acc2[nt] = __builtin_amdgcn_mfma_f32_16x16x32_bf16(a2hi[kf], blo, acc2[nt], 0, 0, 0);
                acc2[nt] = __builtin_amdgcn_mfma_f32_16x16x32_bf16(a2lo[kf], bhi, acc2[nt], 0, 0, 0);
            }
        }

#pragma unroll
        for (int nt = 0; nt < 4; ++nt) {
#pragma unroll
            for (int r = 0; r < 4; ++r) {
                float o = acc2[nt][r] + b2v[nt];
                hout[((size_t)(node0 + quad * 4 + r)) * DIM + nt * 16 + m] = f2bf(o);
            }
        }
    }
}

// Pool stage 1: 4 blocks per graph (16 wave-slots), partial sums -> atomicAdd staging.
__global__ __launch_bounds__(256) void pool_sum_kernel(
    const unsigned short* __restrict__ h, const int* __restrict__ batch,
    float* __restrict__ pooled, int n_nodes) {
    const int g = blockIdx.x >> 2;
    const int p = blockIdx.x & 3;
    const int lane = threadIdx.x & 63;
    const int w = threadIdx.x >> 6;

    int lo = 0, hi = n_nodes;
    while (lo < hi) {
        int mid = (lo + hi) >> 1;
        if (batch[mid] < g) lo = mid + 1; else hi = mid;
    }
    const int s0 = lo;
    hi = n_nodes;
    while (lo < hi) {
        int mid = (lo + hi) >> 1;
        if (batch[mid] < g + 1) lo = mid + 1; else hi = mid;
    }
    const int e0 = lo;

    float acc = 0.f;
    for (int i = s0 + p * 4 + w; i < e0; i += 16)
        acc += bf2f(h[(size_t)i * DIM + lane]);
    atomicAdd(&pooled[g * DIM + lane], acc);
}

// Pool stage 2: one wave per graph: divide by count, readout MLP.
__global__ __launch_bounds__(64) void pool_read_kernel(
    const float* __restrict__ pooled, const int* __restrict__ batch,
    const float* __restrict__ mW1, const float* __restrict__ mb1,
    const float* __restrict__ mW2, const float* __restrict__ mb2,
    float* __restrict__ out, int n_nodes) {
    const int g = blockIdx.x;
    const int lane = threadIdx.x;

    int lo = 0, hi = n_nodes;
    while (lo < hi) {
        int mid = (lo + hi) >> 1;
        if (batch[mid] < g) lo = mid + 1; else hi = mid;
    }
    const int s0 = lo;
    hi = n_nodes;
    while (lo < hi) {
        int mid = (lo + hi) >> 1;
        if (batch[mid] < g + 1) lo = mid + 1; else hi = mid;
    }
    const int e0 = lo;

    float acc = pooled[g * DIM + lane] / fmaxf((float)(e0 - s0), 1.f);

    float t = mb1[lane];
#pragma unroll
    for (int d = 0; d < DIM; ++d) {
        float zd = __shfl(acc, d);
        t = fmaf(zd, mW1[d * DIM + lane], t);
    }
    t = fmaxf(t, 0.f);
    float o = mb2[lane];
#pragma unroll
    for (int d = 0; d < DIM; ++d) {
        float rd = __shfl(t, d);
        o = fmaf(rd, mW2[d * DIM + lane], o);
    }
    out[g * DIM + lane] = o;
}

extern "C" void kernel_launch(void* const* d_in, const int* in_sizes, int n_in,
                              void* d_out, int out_size, void* d_ws, size_t ws_size,
                              hipStream_t stream) {
    const float* x   = (const float*)d_in[0];
    const int*   ei  = (const int*)d_in[1];
    const int*   bat = (const int*)d_in[2];
    const float* Ws1 = (const float*)d_in[3];
    const float* bs1 = (const float*)d_in[4];
    const float* Ws2 = (const float*)d_in[5];
    const float* bs2 = (const float*)d_in[6];
    const float* mW1 = (const float*)d_in[7];
    const float* mb1 = (const float*)d_in[8];
    const float* mW2 = (const float*)d_in[9];
    const float* mb2 = (const float*)d_in[10];
    float* out = (float*)d_out;

    char* ws = (char*)d_ws;
    size_t off = 0;
    auto alloc = [&](size_t bytes) {
        void* p = ws + off;
        off += (bytes + 255) & ~(size_t)255;
        return p;
    };
    int*  esrc    = (int*)alloc((size_t)NB2 * CAP2 * 4);       // 10.0 MB
    int2* meta    = (int2*)alloc((size_t)N_NODES * 8);         // 0.8 MB
    unsigned short* hbfA = (unsigned short*)alloc(((size_t)N_NODES + 1) * DIM * 2);
    unsigned short* hbfB = (unsigned short*)alloc(((size_t)N_NODES + 1) * DIM * 2);
    int*  bcursor = (int*)alloc((size_t)NB2 * 4);
    unsigned short* wpk = (unsigned short*)alloc((size_t)N_LAYERS * 32 * 64 * 8 * 2);  // 160 KB
    float* pooled = (float*)alloc((size_t)N_GRAPHS * DIM * 4); // 64 KB
    int*   pairbuf = (int*)alloc((size_t)NB2 * SUBCAP2 * 4);   // 7.2 MB
    unsigned short* zbig = (unsigned short*)alloc((size_t)N_NODES * DIM * 2);  // 12.8 MB

    const int* src = ei;
    const int* dst = ei + N_EDGES;

    // fused init: x->bf16, prepack, dummy rows, bcursor zero, pooled zero
    cvt_init_kernel<<<(N_NODES * DIM / 4 + 255) / 256, 256, 0, stream>>>(
        (const float4*)x, (ushort4*)hbfA, Ws1, Ws2, wpk, hbfA, hbfB,
        bcursor, pooled, N_NODES * DIM / 4);

    // CSR build: tile-binning with run reservation -> per-bucket padded CSR
    bin_kernel<<<NTILE, 256, 0, stream>>>(src, dst, bcursor, pairbuf);
    csr_kernel<<<NB2, 256, 0, stream>>>(bcursor, pairbuf, esrc, meta);

    const unsigned short* hin = hbfA;
    unsigned short* hout = hbfB;
    for (int l = 0; l < N_LAYERS; ++l) {
        agg_kernel<<<2048, 256, 0, stream>>>(hin, zbig, meta, esrc, N_NODES);
        mlp_mfma_kernel<<<1563, 256, 0, stream>>>(zbig, hout,
                                                  wpk + (size_t)l * 32 * 64 * 8,
                                                  bs1 + (size_t)l * DIM,
                                                  bs2 + (size_t)l * DIM);
        hin = hout;
        hout = (hout == hbfA) ? hbfB : hbfA;
    }
    pool_sum_kernel<<<N_GRAPHS * 4, 256, 0, stream>>>(hin, bat, pooled, N_NODES);
    pool_read_kernel<<<N_GRAPHS, 64, 0, stream>>>(pooled, bat, mW1, mb1, mW2, mb2, out, N_NODES);
}

// Round 13
// 370.718 us; speedup vs baseline: 1.0463x; 1.0463x over previous
//
#include <hip/hip_runtime.h>
#include <hip/hip_bf16.h>

#define N_NODES 100000
#define N_EDGES 1600000
#define DIM 64
#define N_LAYERS 5
#define N_GRAPHS 256

#define NB2 196        // coarse buckets of 512 nodes
#define SUBCAP2 9216   // per-bucket pair capacity: mean 8192, sigma ~90
#define CAP2 12800     // esrc region per bucket (padded CSR worst case)
#define DUMMY N_NODES  // dummy node id; its h row is kept zero
#define TILE 3200      // edges per binning workgroup
#define NTILE 500      // 500 * 3200 = 1.6M
#define MTILES (N_NODES / 16)  // 6250 node-tiles for the MFMA MLP

typedef __attribute__((ext_vector_type(8))) short short8;
typedef __attribute__((ext_vector_type(4))) float float4v;

__global__ void zero_kernel(int* p, int n) {
    int i = blockIdx.x * blockDim.x + threadIdx.x;
    if (i < n) p[i] = 0;
}

// bf16 helpers (bit-level, RNE)
__device__ __forceinline__ unsigned short f2bf(float f) {
    unsigned int u = __float_as_uint(f);
    unsigned int r = (u + 0x7fffu + ((u >> 16) & 1u)) >> 16;
    return (unsigned short)r;
}
__device__ __forceinline__ float bf2f(unsigned short b) {
    return __uint_as_float(((unsigned int)b) << 16);
}

__global__ void zero_dummy_kernel(unsigned short* a, unsigned short* b) {
    int t = threadIdx.x;  // 64
    a[(size_t)DUMMY * DIM + t] = 0;
    b[(size_t)DUMMY * DIM + t] = 0;
}

// x (fp32) -> bf16 rows
__global__ void cvt_kernel(const float4* __restrict__ x, ushort4* __restrict__ hb, int n4) {
    int i = blockIdx.x * blockDim.x + threadIdx.x;
    if (i < n4) {
        float4 v = x[i];
        ushort4 o;
        o.x = f2bf(v.x); o.y = f2bf(v.y); o.z = f2bf(v.z); o.w = f2bf(v.w);
        hb[i] = o;
    }
}

// Prepack W1/W2 of all layers into MFMA B-fragment order, hi/lo bf16 split.
__global__ void prepack_kernel(const float* __restrict__ Ws1, const float* __restrict__ Ws2,
                               unsigned short* __restrict__ wpk) {
    int t = blockIdx.x * blockDim.x + threadIdx.x;  // 5*32*64 = 10240 threads
    if (t >= N_LAYERS * 32 * 64) return;
    int lane = t & 63;
    int frag = (t >> 6) & 31;
    int l = t >> 11;
    int kf = frag & 1;
    int nt = (frag >> 1) & 3;
    int split = (frag >> 3) & 1;
    int mat = (frag >> 4) & 1;
    const float* W = (mat ? Ws2 : Ws1) + (size_t)l * DIM * DIM;
    unsigned short outv[8];
#pragma unroll
    for (int j = 0; j < 8; ++j) {
        int k = kf * 32 + ((lane >> 4) << 3) + j;
        int n = nt * 16 + (lane & 15);
        float v = W[k * DIM + n];
        unsigned short hi = f2bf(v);
        outv[j] = split ? f2bf(v - bf2f(hi)) : hi;
    }
    ushort4* dst = (ushort4*)(wpk + ((size_t)(l * 32 + frag) * 64 + lane) * 8);
    dst[0] = make_ushort4(outv[0], outv[1], outv[2], outv[3]);
    dst[1] = make_ushort4(outv[4], outv[5], outv[6], outv[7]);
}

// Phase A: tile-binning with run reservation (one global atomic per bucket per tile).
__global__ __launch_bounds__(256) void bin_kernel(
    const int* __restrict__ src, const int* __restrict__ dst,
    int* __restrict__ bcursor, int* __restrict__ pairbuf) {
    __shared__ int hcnt[NB2];
    __shared__ int gbase[NB2];
    __shared__ int lcur[NB2];
    const int tid = threadIdx.x;
    const int base = blockIdx.x * TILE;

    for (int l = tid; l < NB2; l += 256) { hcnt[l] = 0; lcur[l] = 0; }
    __syncthreads();
    for (int j = tid; j < TILE; j += 256) {
        int d = dst[base + j];
        atomicAdd(&hcnt[d >> 9], 1);
    }
    __syncthreads();
    for (int l = tid; l < NB2; l += 256)
        gbase[l] = atomicAdd(&bcursor[l], hcnt[l]);
    __syncthreads();
    for (int j = tid; j < TILE; j += 256) {
        int s = src[base + j];
        int d = dst[base + j];
        int b = d >> 9;
        int r = atomicAdd(&lcur[b], 1);
        int pos = gbase[b] + r;
        if (pos < SUBCAP2) pairbuf[b * SUBCAP2 + pos] = (s << 9) | (d & 511);
    }
}

// Phase B: one WG per coarse bucket (512 nodes). Count -> padded scan -> scatter.
__global__ __launch_bounds__(256) void csr_kernel(
    const int* __restrict__ bcursor, const int* __restrict__ pairbuf,
    int* __restrict__ esrc, int2* __restrict__ meta) {
    __shared__ int lcnt[512];
    __shared__ int loff[512];
    __shared__ int lcur[512];
    __shared__ int s2[256];
    const int b = blockIdx.x;
    const int tid = threadIdx.x;
    int ec = bcursor[b];
    if (ec > SUBCAP2) ec = SUBCAP2;
    const int* pp = pairbuf + b * SUBCAP2;

    for (int l = tid; l < 512; l += 256) lcnt[l] = 0;
    __syncthreads();
    for (int j = tid; j < ec; j += 256) atomicAdd(&lcnt[pp[j] & 511], 1);
    __syncthreads();

    int c0 = (lcnt[2 * tid] + 7) & ~7;
    int c1 = (lcnt[2 * tid + 1] + 7) & ~7;
    s2[tid] = c0 + c1;
    __syncthreads();
    for (int off = 1; off < 256; off <<= 1) {
        int v = (tid >= off) ? s2[tid - off] : 0;
        __syncthreads();
        s2[tid] += v;
        __syncthreads();
    }
    int exc = s2[tid] - (c0 + c1);
    loff[2 * tid] = exc;
    loff[2 * tid + 1] = exc + c0;
    __syncthreads();

    int* eb = esrc + (size_t)b * CAP2;
    for (int l = tid; l < 512; l += 256) {
        int st = loff[l];
        int cn = lcnt[l];
        int cp = (cn + 7) & ~7;
        lcur[l] = st;
        int node = b * 512 + l;
        if (node < N_NODES) meta[node] = make_int2(b * CAP2 + st, cp);
        for (int j = cn; j < cp; ++j) eb[st + j] = DUMMY;
    }
    __syncthreads();

    for (int j = tid; j < ec; j += 256) {
        int p = pp[j];
        int pos = atomicAdd(&lcur[p & 511], 1);
        eb[pos] = p >> 9;
    }
}

__device__ __forceinline__ void acc8(float* acc, uint4 v) {
    acc[0] += __uint_as_float(v.x << 16);
    acc[1] += __uint_as_float(v.x & 0xffff0000u);
    acc[2] += __uint_as_float(v.y << 16);
    acc[3] += __uint_as_float(v.y & 0xffff0000u);
    acc[4] += __uint_as_float(v.z << 16);
    acc[5] += __uint_as_float(v.z & 0xffff0000u);
    acc[6] += __uint_as_float(v.w << 16);
    acc[7] += __uint_as_float(v.w & 0xffff0000u);
}

// Aggregation: z_i = h_i + sum_j h_j, h rows bf16 (128 B).
// 2 nodes/wave, 16KB LDS, 32 waves/CU; z stored bf16 (fp32 accumulate).
__global__ __launch_bounds__(256) void agg_kernel(
    const unsigned short* __restrict__ hin, unsigned short* __restrict__ z,
    const int2* __restrict__ meta, const int* __restrict__ esrc, int n_nodes) {
    __shared__ float zbuf[4][2][8][DIM];  // 16 KB
    const int lane = threadIdx.x & 63;
    const int wv = threadIdx.x >> 6;
    const int grp = lane >> 3;
    const int sub = lane & 7;
    const int wave_id = (blockIdx.x * blockDim.x + threadIdx.x) >> 6;
    const int n_waves = (gridDim.x * blockDim.x) >> 6;
    const uint4* __restrict__ h4 = (const uint4*)hin;

    for (int ii = wave_id; 2 * ii < n_nodes; ii += n_waves) {
        const int iA = 2 * ii;
        const int iB = iA + 1;
        const int2 mA = meta[iA];
        const int2 mB = meta[iB];
        const float selfA = bf2f(hin[iA * DIM + lane]);
        const float selfB = bf2f(hin[iB * DIM + lane]);
        const int* eA = esrc + mA.x + grp;
        const int* eB = esrc + mB.x + grp;
        const int nA = mA.y, nB = mB.y;

        float accA[8], accB[8];
#pragma unroll
        for (int j = 0; j < 8; ++j) { accA[j] = 0.f; accB[j] = 0.f; }

        int k = 0;
        const int nmin = (nA < nB) ? nA : nB;
        for (; k < nmin; k += 8) {
            const int ia = eA[k];
            const int ib = eB[k];
            uint4 va = h4[ia * 8 + sub];
            uint4 vb = h4[ib * 8 + sub];
            acc8(accA, va);
            acc8(accB, vb);
        }
        for (int kk = k; kk < nA; kk += 8) {
            uint4 va = h4[eA[kk] * 8 + sub];
            acc8(accA, va);
        }
        for (int kk = k; kk < nB; kk += 8) {
            uint4 vb = h4[eB[kk] * 8 + sub];
            acc8(accB, vb);
        }

        *((float4*)&zbuf[wv][0][grp][sub * 8 + 0]) = make_float4(accA[0], accA[1], accA[2], accA[3]);
        *((float4*)&zbuf[wv][0][grp][sub * 8 + 4]) = make_float4(accA[4], accA[5], accA[6], accA[7]);
        *((float4*)&zbuf[wv][1][grp][sub * 8 + 0]) = make_float4(accB[0], accB[1], accB[2], accB[3]);
        *((float4*)&zbuf[wv][1][grp][sub * 8 + 4]) = make_float4(accB[4], accB[5], accB[6], accB[7]);
        __builtin_amdgcn_wave_barrier();
        float zA = selfA, zB = selfB;
#pragma unroll
        for (int g = 0; g < 8; ++g) {
            zA += zbuf[wv][0][g][lane];
            zB += zbuf[wv][1][g][lane];
        }
        z[iA * DIM + lane] = f2bf(zA);
        z[iB * DIM + lane] = f2bf(zB);
        __builtin_amdgcn_wave_barrier();
    }
}

__device__ __forceinline__ short8 load_frag(const unsigned short* __restrict__ wl, int frag, int lane) {
    union { uint4 u; short8 s; } c;
    c.u = *(const uint4*)(wl + ((size_t)(frag * 64 + lane)) * 8);
    return c.s;
}

__device__ __forceinline__ void split8(const float* v, short8& hi, short8& lo) {
#pragma unroll
    for (int j = 0; j < 8; ++j) {
        unsigned short h = f2bf(v[j]);
        hi[j] = (short)h;
        lo[j] = (short)f2bf(v[j] - bf2f(h));
    }
}

// MFMA MLP: h = relu(z@W1+b1)@W2+b2 ; z bf16 in, h bf16 out.
// GEMM1: A exactly bf16 -> 2 MFMAs per (nt,kf). GEMM2 keeps fp32 hi/lo split (3 MFMAs).
__global__ __launch_bounds__(256) void mlp_mfma_kernel(
    const unsigned short* __restrict__ z, unsigned short* __restrict__ hout,
    const unsigned short* __restrict__ wl,
    const float* __restrict__ b1, const float* __restrict__ b2) {
    __shared__ float tbuf[4][16][68];
    const int lane = threadIdx.x & 63;
    const int wv = threadIdx.x >> 6;
    const int m = lane & 15;
    const int quad = lane >> 4;
    const int wave_id = (blockIdx.x * blockDim.x + threadIdx.x) >> 6;
    const int n_waves = (gridDim.x * blockDim.x) >> 6;

    float b1v[4], b2v[4];
#pragma unroll
    for (int nt = 0; nt < 4; ++nt) {
        b1v[nt] = b1[nt * 16 + m];
        b2v[nt] = b2[nt * 16 + m];
    }

    for (int tile = wave_id; tile < MTILES; tile += n_waves) {
        const int node0 = tile * 16;

        short8 a1[2];
#pragma unroll
        for (int kf = 0; kf < 2; ++kf) {
            union { uint4 u; short8 s; } c;
            c.u = *(const uint4*)(z + ((size_t)(node0 + m)) * DIM + kf * 32 + quad * 8);
            a1[kf] = c.s;
        }

        float4v acc1[4] = {};
#pragma unroll
        for (int nt = 0; nt < 4; ++nt) {
#pragma unroll
            for (int kf = 0; kf < 2; ++kf) {
                short8 bhi = load_frag(wl, ((0 * 2 + 0) * 4 + nt) * 2 + kf, lane);
                short8 blo = load_frag(wl, ((0 * 2 + 1) * 4 + nt) * 2 + kf, lane);
                acc1[nt] = __builtin_amdgcn_mfma_f32_16x16x32_bf16(a1[kf], bhi, acc1[nt], 0, 0, 0);
                acc1[nt] = __builtin_amdgcn_mfma_f32_16x16x32_bf16(a1[kf], blo, acc1[nt], 0, 0, 0);
            }
        }

#pragma unroll
        for (int nt = 0; nt < 4; ++nt) {
#pragma unroll
            for (int r = 0; r < 4; ++r) {
                float tv = acc1[nt][r] + b1v[nt];
                tbuf[wv][quad * 4 + r][nt * 16 + m] = fmaxf(tv, 0.f);
            }
        }
        __builtin_amdgcn_wave_barrier();

        short8 a2hi[2], a2lo[2];
#pragma unroll
        for (int kf = 0; kf < 2; ++kf) {
            const float4* tp = (const float4*)&tbuf[wv][m][kf * 32 + quad * 8];
            float4 t0 = tp[0];
            float4 t1 = tp[1];
            float v[8] = {t0.x, t0.y, t0.z, t0.w, t1.x, t1.y, t1.z, t1.w};
            split8(v, a2hi[kf], a2lo[kf]);
        }
        __builtin_amdgcn_wave_barrier();

        float4v acc2[4] = {};
#pragma unroll
        for (int nt = 0; nt < 4; ++nt) {
#pragma unroll
            for (int kf = 0; kf < 2; ++kf) {
                short8 bhi = load_frag(wl, ((1 * 2 + 0) * 4 + nt) * 2 + kf, lane);
                short8 blo = load_frag(wl, ((1 * 2 + 1) * 4 + nt) * 2 + kf, lane);
                acc2[nt] = __builtin_amdgcn_mfma_f32_16x16x32_bf16(a2hi[kf], bhi, acc2[nt], 0, 0, 0);
                acc2[nt] = __builtin_amdgcn_mfma_f32_16x16x32_bf16(a2hi[kf], blo, acc2[nt], 0, 0, 0);
                acc2[nt] = __builtin_amdgcn_mfma_f32_16x16x32_bf16(a2lo[kf], bhi, acc2[nt], 0, 0, 0);
            }
        }

#pragma unroll
        for (int nt = 0; nt < 4; ++nt) {
#pragma unroll
            for (int r = 0; r < 4; ++r) {
                float o = acc2[nt][r] + b2v[nt];
                hout[((size_t)(node0 + quad * 4 + r)) * DIM + nt * 16 + m] = f2bf(o);
            }
        }
    }
}

// Block (4 waves) per graph: binary-search node range, mean-pool (bf16 in), readout MLP.
__global__ __launch_bounds__(256) void pool_mlp_kernel(
    const unsigned short* __restrict__ h, const int* __restrict__ batch,
    const float* __restrict__ mW1, const float* __restrict__ mb1,
    const float* __restrict__ mW2, const float* __restrict__ mb2,
    float* __restrict__ out, int n_nodes) {
    __shared__ float part[4][DIM];
    const int g = blockIdx.x;
    const int lane = threadIdx.x & 63;
    const int w = threadIdx.x >> 6;

    int lo = 0, hi = n_nodes;
    while (lo < hi) {
        int mid = (lo + hi) >> 1;
        if (batch[mid] < g) lo = mid + 1; else hi = mid;
    }
    const int s0 = lo;
    hi = n_nodes;
    while (lo < hi) {
        int mid = (lo + hi) >> 1;
        if (batch[mid] < g + 1) lo = mid + 1; else hi = mid;
    }
    const int e0 = lo;

    float acc = 0.f;
    int i = s0 + w;
    for (; i + 12 < e0; i += 16) {
        float v0 = bf2f(h[i * DIM + lane]);
        float v1 = bf2f(h[(i + 4) * DIM + lane]);
        float v2 = bf2f(h[(i + 8) * DIM + lane]);
        float v3 = bf2f(h[(i + 12) * DIM + lane]);
        acc += (v0 + v1) + (v2 + v3);
    }
    for (; i < e0; i += 4) acc += bf2f(h[i * DIM + lane]);
    part[w][lane] = acc;
    __syncthreads();

    if (w == 0) {
        acc = (part[0][lane] + part[1][lane]) + (part[2][lane] + part[3][lane]);
        float cntf = (float)(e0 - s0);
        acc /= fmaxf(cntf, 1.f);

        float t = mb1[lane];
#pragma unroll
        for (int d = 0; d < DIM; ++d) {
            float zd = __shfl(acc, d);
            t = fmaf(zd, mW1[d * DIM + lane], t);
        }
        t = fmaxf(t, 0.f);
        float o = mb2[lane];
#pragma unroll
        for (int d = 0; d < DIM; ++d) {
            float rd = __shfl(t, d);
            o = fmaf(rd, mW2[d * DIM + lane], o);
        }
        out[g * DIM + lane] = o;
    }
}

extern "C" void kernel_launch(void* const* d_in, const int* in_sizes, int n_in,
                              void* d_out, int out_size, void* d_ws, size_t ws_size,
                              hipStream_t stream) {
    const float* x   = (const float*)d_in[0];
    const int*   ei  = (const int*)d_in[1];
    const int*   bat = (const int*)d_in[2];
    const float* Ws1 = (const float*)d_in[3];
    const float* bs1 = (const float*)d_in[4];
    const float* Ws2 = (const float*)d_in[5];
    const float* bs2 = (const float*)d_in[6];
    const float* mW1 = (const float*)d_in[7];
    const float* mb1 = (const float*)d_in[8];
    const float* mW2 = (const float*)d_in[9];
    const float* mb2 = (const float*)d_in[10];
    float* out = (float*)d_out;

    char* ws = (char*)d_ws;
    size_t off = 0;
    auto alloc = [&](size_t bytes) {
        void* p = ws + off;
        off += (bytes + 255) & ~(size_t)255;
        return p;
    };
    int*  esrc    = (int*)alloc((size_t)NB2 * CAP2 * 4);       // 10.0 MB
    int2* meta    = (int2*)alloc((size_t)N_NODES * 8);         // 0.8 MB
    unsigned short* hbfA = (unsigned short*)alloc(((size_t)N_NODES + 1) * DIM * 2);
    unsigned short* hbfB = (unsigned short*)alloc(((size_t)N_NODES + 1) * DIM * 2);
    int*  bcursor = (int*)alloc((size_t)NB2 * 4);
    unsigned short* wpk = (unsigned short*)alloc((size_t)N_LAYERS * 32 * 64 * 8 * 2);  // 160 KB
    int*   pairbuf = (int*)alloc((size_t)NB2 * SUBCAP2 * 4);   // 7.2 MB
    unsigned short* zbig = (unsigned short*)alloc((size_t)N_NODES * DIM * 2);  // 12.8 MB

    const int* src = ei;
    const int* dst = ei + N_EDGES;

    // CSR build: tile-binning with run reservation -> per-bucket padded CSR
    zero_kernel<<<1, 256, 0, stream>>>(bcursor, NB2);
    bin_kernel<<<NTILE, 256, 0, stream>>>(src, dst, bcursor, pairbuf);
    csr_kernel<<<NB2, 256, 0, stream>>>(bcursor, pairbuf, esrc, meta);

    // weight prepack (B-fragment order, hi/lo split), x -> bf16, dummy rows zeroed
    prepack_kernel<<<(N_LAYERS * 32 * 64 + 255) / 256, 256, 0, stream>>>(Ws1, Ws2, wpk);
    zero_dummy_kernel<<<1, 64, 0, stream>>>(hbfA, hbfB);
    cvt_kernel<<<(N_NODES * DIM / 4 + 255) / 256, 256, 0, stream>>>(
        (const float4*)x, (ushort4*)hbfA, N_NODES * DIM / 4);

    const unsigned short* hin = hbfA;
    unsigned short* hout = hbfB;
    for (int l = 0; l < N_LAYERS; ++l) {
        agg_kernel<<<2048, 256, 0, stream>>>(hin, zbig, meta, esrc, N_NODES);
        mlp_mfma_kernel<<<1024, 256, 0, stream>>>(zbig, hout,
                                                  wpk + (size_t)l * 32 * 64 * 8,
                                                  bs1 + (size_t)l * DIM,
                                                  bs2 + (size_t)l * DIM);
        hin = hout;
        hout = (hout == hbfA) ? hbfB : hbfA;
    }
    pool_mlp_kernel<<<N_GRAPHS, 256, 0, stream>>>(hin, bat, mW1, mb1, mW2, mb2, out, N_NODES);
}